// Round 10
// baseline (460.105 us; speedup 1.0000x reference)
//
#include <hip/hip_runtime.h>
#include <math.h>

#define BUCKET_SHIFT 8  // 256 nodes per bucket

typedef short s8v __attribute__((ext_vector_type(8)));   // 8 bf16 (4 VGPRs)
typedef float f4v __attribute__((ext_vector_type(4)));   // 4 fp32 acc
typedef unsigned short u16;

__device__ inline u16 f2bf(float f) {  // RNE fp32->bf16
    unsigned u = __float_as_uint(f);
    return (u16)((u + 0x7FFFu + ((u >> 16) & 1u)) >> 16);
}
__device__ inline float bf2f(u16 s) { return __uint_as_float(((unsigned)s) << 16); }
__device__ inline float blo(unsigned x) { return __uint_as_float(x << 16); }
__device__ inline float bhi(unsigned x) { return __uint_as_float(x & 0xffff0000u); }

// ---------------- CSR build (bucketed, no per-node global atomics) ----------------

__global__ __launch_bounds__(256) void bucket_count_kernel(const int* __restrict__ dst,
                                                           int* __restrict__ bucketCnt,
                                                           int n_edges, int nbuckets) {
    __shared__ int hist[512];
    int tid = threadIdx.x;
    for (int j = tid; j < nbuckets; j += 256) hist[j] = 0;
    __syncthreads();
    int e0 = blockIdx.x * 16384;
    int e1 = min(e0 + 16384, n_edges);
    for (int e = e0 + tid; e < e1; e += 256)
        atomicAdd(&hist[dst[e] >> BUCKET_SHIFT], 1);
    __syncthreads();
    for (int j = tid; j < nbuckets; j += 256) {
        int c = hist[j];
        if (c > 0) atomicAdd(&bucketCnt[j], c);
    }
}

__global__ __launch_bounds__(512) void scan_buckets_kernel(const int* __restrict__ bucketCnt,
                                                           int* __restrict__ bucketBase,
                                                           int* __restrict__ gcursor,
                                                           int nbuckets) {
    int tid = threadIdx.x;
    int c = (tid < nbuckets) ? bucketCnt[tid] : 0;
    int lane = tid & 63, wave = tid >> 6;
    int v = c;
#pragma unroll
    for (int off = 1; off < 64; off <<= 1) {
        int t = __shfl_up(v, off, 64);
        if (lane >= off) v += t;
    }
    __shared__ int wsum[8], woff[8];
    if (lane == 63) wsum[wave] = v;
    __syncthreads();
    if (tid == 0) {
        int run = 0;
#pragma unroll
        for (int w = 0; w < 8; ++w) { woff[w] = run; run += wsum[w]; }
    }
    __syncthreads();
    int excl = woff[wave] + (v - c);
    if (tid <= nbuckets) bucketBase[tid] = excl;
    if (tid < nbuckets) gcursor[tid] = excl;
}

__global__ __launch_bounds__(256) void bucket_scatter_kernel(const int* __restrict__ src,
                                                             const int* __restrict__ dst,
                                                             int* __restrict__ gcursor,
                                                             unsigned* __restrict__ interm,
                                                             int n_edges, int nbuckets) {
    __shared__ int hist[512];
    __shared__ int gbase[512];
    int tid = threadIdx.x;
    for (int j = tid; j < nbuckets; j += 256) hist[j] = 0;
    __syncthreads();
    int e0 = blockIdx.x * 16384;
    int e1 = min(e0 + 16384, n_edges);
    for (int e = e0 + tid; e < e1; e += 256)
        atomicAdd(&hist[dst[e] >> BUCKET_SHIFT], 1);
    __syncthreads();
    for (int j = tid; j < nbuckets; j += 256) {
        int c = hist[j];
        gbase[j] = c > 0 ? atomicAdd(&gcursor[j], c) : 0;
        hist[j] = 0;
    }
    __syncthreads();
    for (int e = e0 + tid; e < e1; e += 256) {
        int d = dst[e];
        int s = src[e];
        int j = d >> BUCKET_SHIFT;
        int p = atomicAdd(&hist[j], 1);
        interm[gbase[j] + p] = ((unsigned)s << 8) | (unsigned)(d & 255);
    }
}

__global__ __launch_bounds__(256) void bucket_build_kernel(const unsigned* __restrict__ interm,
                                                           const int* __restrict__ bucketBase,
                                                           int* __restrict__ rowptr,
                                                           float* __restrict__ invd,
                                                           int* __restrict__ ssrc, int n_nodes) {
    __shared__ int cnt[256];
    __shared__ int cur[256];
    __shared__ int wsum[4], woff[4];
    int tid = threadIdx.x;
    int nb0 = blockIdx.x << BUCKET_SHIFT;
    int base = bucketBase[blockIdx.x];
    int end = bucketBase[blockIdx.x + 1];
    cnt[tid] = 0;
    __syncthreads();
    for (int e = base + tid; e < end; e += 256)
        atomicAdd(&cnt[interm[e] & 255u], 1);
    __syncthreads();
    int c = cnt[tid];
    int lane = tid & 63, wave = tid >> 6;
    int v = c;
#pragma unroll
    for (int off = 1; off < 64; off <<= 1) {
        int t = __shfl_up(v, off, 64);
        if (lane >= off) v += t;
    }
    if (lane == 63) wsum[wave] = v;
    __syncthreads();
    if (tid == 0) {
        int run = 0;
#pragma unroll
        for (int w = 0; w < 4; ++w) { woff[w] = run; run += wsum[w]; }
    }
    __syncthreads();
    int excl = woff[wave] + (v - c);
    int node = nb0 + tid;
    if (node < n_nodes) {
        rowptr[node] = base + excl;
        invd[node] = c > 0 ? 1.0f / (float)c : 0.0f;
        if (node == n_nodes - 1) rowptr[n_nodes] = base + excl + c;
    }
    cur[tid] = base + excl;
    __syncthreads();
    for (int e = base + tid; e < end; e += 256) {
        unsigned p = interm[e];
        int pos = atomicAdd(&cur[p & 255u], 1);
        ssrc[pos] = (int)(p >> 8);
    }
}

// ---------------- x -> bf16 ----------------
__global__ __launch_bounds__(256) void convert_kernel(const float* __restrict__ x,
                                                      u16* __restrict__ xb, long total8) {
    long i = (long)blockIdx.x * 256 + threadIdx.x;
    if (i >= total8) return;
    const float* p = &x[i * 8];
    float4 lo = *(const float4*)p;
    float4 hi = *(const float4*)(p + 4);
    union { u16 u[8]; s8v v; } t;
    t.u[0] = f2bf(lo.x); t.u[1] = f2bf(lo.y); t.u[2] = f2bf(lo.z); t.u[3] = f2bf(lo.w);
    t.u[4] = f2bf(hi.x); t.u[5] = f2bf(hi.y); t.u[6] = f2bf(hi.z); t.u[7] = f2bf(hi.w);
    *(s8v*)&xb[i * 8] = t.v;
}

// ---------------- weight packing into MFMA fragment order ----------------
__global__ void pack01_kernel(const float* __restrict__ Wl, const float* __restrict__ Wr,
                              u16* __restrict__ out) {
    int idx = blockIdx.x * 256 + threadIdx.x;  // 256*128
    if (idx >= 32768) return;
    int k = idx >> 7, c = idx & 127;
    float v = (k < 128) ? Wl[k * 128 + c] : Wr[(k - 128) * 128 + c];
    int kt = k >> 5, q = (k >> 3) & 3, j = k & 7, ct = c >> 4, n = c & 15;
    out[(((kt * 8 + ct) * 64 + q * 16 + n) << 3) + j] = f2bf(v);
}

__global__ void packl2_kernel(const float* __restrict__ Wl, const float* __restrict__ Wr,
                              u16* __restrict__ out) {
    int idx = blockIdx.x * 256 + threadIdx.x;  // 128*128
    if (idx >= 16384) return;
    int k = idx >> 7, c = idx & 127;
    float v = 0.f;
    if (c < 47) v = Wl[k * 47 + c];
    else if (c >= 64 && c < 111) v = Wr[k * 47 + (c - 64)];
    int kt = k >> 5, q = (k >> 3) & 3, j = k & 7, ct = c >> 4, n = c & 15;
    out[(((kt * 8 + ct) * 64 + q * 16 + n) << 3) + j] = f2bf(v);
}

// ---------------- fused SAGE layer: uint4 gather-agg -> LDS A-tile -> MFMA ----------------
// hout = relu([mean_agg(hin) | hin] @ Wfrag + b). hin/hout distinct buffers.
// Phase 1: 16 groups x 16 lanes; lane covers 16B of the 256B row; x8 unrolled gathers.
__global__ __launch_bounds__(256) void sage_layer_mfma(const uint4* __restrict__ hin4,
                                                       const int* __restrict__ rowptr,
                                                       const int* __restrict__ ssrc,
                                                       const float* __restrict__ invd,
                                                       const u16* __restrict__ Wfrag,
                                                       const float* __restrict__ bias,
                                                       u16* __restrict__ hout, int n_nodes) {
    __shared__ u16 As[32][264];
    __shared__ int rp[33];
    int tid = threadIdx.x;
    int n0 = blockIdx.x * 32;
    if (tid < 33) rp[tid] = rowptr[min(n0 + tid, n_nodes)];
    __syncthreads();

    int d = tid & 15, grp = tid >> 4;  // 16 groups of 16 lanes

#pragma unroll
    for (int pass = 0; pass < 2; ++pass) {
        int row = pass * 16 + grp;
        int n = n0 + row;
        float a0 = 0.f, a1 = 0.f, a2 = 0.f, a3 = 0.f;
        float a4 = 0.f, a5 = 0.f, a6 = 0.f, a7 = 0.f;
        int e = rp[row], e1 = rp[row + 1];
        for (; e + 7 < e1; e += 8) {
            int s[8];
#pragma unroll
            for (int j = 0; j < 8; ++j) s[j] = ssrc[e + j];
            uint4 v[8];
#pragma unroll
            for (int j = 0; j < 8; ++j) v[j] = hin4[(size_t)s[j] * 16 + d];
#pragma unroll
            for (int j = 0; j < 8; ++j) {
                a0 += blo(v[j].x); a1 += bhi(v[j].x);
                a2 += blo(v[j].y); a3 += bhi(v[j].y);
                a4 += blo(v[j].z); a5 += bhi(v[j].z);
                a6 += blo(v[j].w); a7 += bhi(v[j].w);
            }
        }
        for (; e + 1 < e1; e += 2) {
            uint4 v0 = hin4[(size_t)ssrc[e] * 16 + d];
            uint4 v1 = hin4[(size_t)ssrc[e + 1] * 16 + d];
            a0 += blo(v0.x) + blo(v1.x); a1 += bhi(v0.x) + bhi(v1.x);
            a2 += blo(v0.y) + blo(v1.y); a3 += bhi(v0.y) + bhi(v1.y);
            a4 += blo(v0.z) + blo(v1.z); a5 += bhi(v0.z) + bhi(v1.z);
            a6 += blo(v0.w) + blo(v1.w); a7 += bhi(v0.w) + bhi(v1.w);
        }
        if (e < e1) {
            uint4 v0 = hin4[(size_t)ssrc[e] * 16 + d];
            a0 += blo(v0.x); a1 += bhi(v0.x);
            a2 += blo(v0.y); a3 += bhi(v0.y);
            a4 += blo(v0.z); a5 += bhi(v0.z);
            a6 += blo(v0.w); a7 += bhi(v0.w);
        }
        float w = (n < n_nodes) ? invd[n] : 0.f;
        uint4 o;
        o.x = (unsigned)f2bf(a0 * w) | ((unsigned)f2bf(a1 * w) << 16);
        o.y = (unsigned)f2bf(a2 * w) | ((unsigned)f2bf(a3 * w) << 16);
        o.z = (unsigned)f2bf(a4 * w) | ((unsigned)f2bf(a5 * w) << 16);
        o.w = (unsigned)f2bf(a6 * w) | ((unsigned)f2bf(a7 * w) << 16);
        *(uint4*)&As[row][d * 8] = o;
    }

    // phase 2: stage self rows into As cols 128..255
    const u16* hin = (const u16*)hin4;
    for (int i = tid; i < 512; i += 256) {
        int row = i >> 4, c8 = i & 15;
        int n = n0 + row;
        s8v t = (s8v){0, 0, 0, 0, 0, 0, 0, 0};
        if (n < n_nodes) t = *(const s8v*)&hin[(size_t)n * 128 + c8 * 8];
        *(s8v*)&As[row][128 + c8 * 8] = t;
    }
    __syncthreads();

    // phase 3: MFMA, K=256
    int wave = tid >> 6, lane = tid & 63;
    int rt = wave & 1, ch = wave >> 1;
    int m = lane & 15, q = lane >> 4;

    f4v acc[4];
#pragma unroll
    for (int c = 0; c < 4; ++c) acc[c] = (f4v){0.f, 0.f, 0.f, 0.f};

#pragma unroll
    for (int kt = 0; kt < 8; ++kt) {
        s8v a = *(const s8v*)&As[rt * 16 + m][kt * 32 + q * 8];
#pragma unroll
        for (int c = 0; c < 4; ++c) {
            int ctg = ch * 4 + c;
            s8v b = *(const s8v*)&Wfrag[(((size_t)kt * 8 + ctg) * 64 + lane) * 8];
            acc[c] = __builtin_amdgcn_mfma_f32_16x16x32_bf16(a, b, acc[c], 0, 0, 0);
        }
    }

#pragma unroll
    for (int c = 0; c < 4; ++c) {
        int col = ch * 64 + c * 16 + m;
        float bc = bias[col];
#pragma unroll
        for (int r = 0; r < 4; ++r) {
            int n = n0 + rt * 16 + q * 4 + r;
            if (n < n_nodes)
                hout[(size_t)n * 128 + col] = f2bf(fmaxf(acc[c][r] + bc, 0.f));
        }
    }
}

// ---------------- MFMA GEMM: [Gn|Gs] = h @ Wfrag2 bf16, K=128 ----------------
__global__ __launch_bounds__(256) void gemmG_mfma(const u16* __restrict__ h,
                                                  const u16* __restrict__ Wfrag,
                                                  u16* __restrict__ Gn,
                                                  u16* __restrict__ Gs, int n_nodes) {
    __shared__ u16 As[32][136];
    int tid = threadIdx.x;
    int n0 = blockIdx.x * 32;
    for (int i = tid; i < 512; i += 256) {
        int row = i >> 4, c8 = i & 15;
        int n = n0 + row;
        s8v t = (s8v){0, 0, 0, 0, 0, 0, 0, 0};
        if (n < n_nodes) t = *(const s8v*)&h[(size_t)n * 128 + c8 * 8];
        *(s8v*)&As[row][c8 * 8] = t;
    }
    __syncthreads();

    int wave = tid >> 6, lane = tid & 63;
    int rt = wave & 1, ch = wave >> 1;
    int m = lane & 15, q = lane >> 4;

    f4v acc[4];
#pragma unroll
    for (int c = 0; c < 4; ++c) acc[c] = (f4v){0.f, 0.f, 0.f, 0.f};

#pragma unroll
    for (int kt = 0; kt < 4; ++kt) {
        s8v a = *(const s8v*)&As[rt * 16 + m][kt * 32 + q * 8];
#pragma unroll
        for (int c = 0; c < 4; ++c) {
            int ctg = ch * 4 + c;
            s8v b = *(const s8v*)&Wfrag[(((size_t)kt * 8 + ctg) * 64 + lane) * 8];
            acc[c] = __builtin_amdgcn_mfma_f32_16x16x32_bf16(a, b, acc[c], 0, 0, 0);
        }
    }

    u16* Gbase = (ch == 0) ? Gn : Gs;
#pragma unroll
    for (int c = 0; c < 4; ++c) {
        int col = c * 16 + m;
#pragma unroll
        for (int r = 0; r < 4; ++r) {
            int n = n0 + rt * 16 + q * 4 + r;
            if (n < n_nodes) Gbase[(size_t)n * 64 + col] = f2bf(acc[c][r]);
        }
    }
}

// ---------------- layer-2 epilogue: 4-edges/wave uint2 gather + log_softmax ----------------
// One wave per node. lane = (g in [0,4), t in [0,16)); group g takes every 4th edge;
// lane t covers cols 4t..4t+3 (uint2 = 8B of the 128B Gn row).
__global__ __launch_bounds__(256) void out_kernel(const uint2* __restrict__ Gn2,
                                                  const u16* __restrict__ Gs,
                                                  const int* __restrict__ rowptr,
                                                  const int* __restrict__ ssrc,
                                                  const float* __restrict__ inv_deg,
                                                  const float* __restrict__ bias,
                                                  float* __restrict__ out, int n_nodes) {
    int lane = threadIdx.x & 63;
    int n = blockIdx.x * 4 + (threadIdx.x >> 6);
    if (n >= n_nodes) return;
    int g = lane >> 4, t = lane & 15;
    int e0 = rowptr[n], e1 = rowptr[n + 1];
    float a0 = 0.f, a1 = 0.f, a2 = 0.f, a3 = 0.f;
    int e = e0 + g;
    for (; e + 28 < e1; e += 32) {  // 8 iterations of stride 4
        int s[8];
#pragma unroll
        for (int j = 0; j < 8; ++j) s[j] = ssrc[e + j * 4];
        uint2 v[8];
#pragma unroll
        for (int j = 0; j < 8; ++j) v[j] = Gn2[(size_t)s[j] * 16 + t];
#pragma unroll
        for (int j = 0; j < 8; ++j) {
            a0 += blo(v[j].x); a1 += bhi(v[j].x);
            a2 += blo(v[j].y); a3 += bhi(v[j].y);
        }
    }
    for (; e < e1; e += 4) {
        uint2 v = Gn2[(size_t)ssrc[e] * 16 + t];
        a0 += blo(v.x); a1 += bhi(v.x);
        a2 += blo(v.y); a3 += bhi(v.y);
    }
    // fold the 4 edge-groups
#pragma unroll
    for (int off = 16; off <= 32; off <<= 1) {
        a0 += __shfl_xor(a0, off, 64);
        a1 += __shfl_xor(a1, off, 64);
        a2 += __shfl_xor(a2, off, 64);
        a3 += __shfl_xor(a3, off, 64);
    }
    float id = inv_deg[n];
    int c0 = t * 4;
    float vv[4];
    float am[4] = {a0, a1, a2, a3};
    float mx = -INFINITY;
#pragma unroll
    for (int c = 0; c < 4; ++c) {
        int col = c0 + c;
        if (col < 47) {
            vv[c] = am[c] * id + bf2f(Gs[(size_t)n * 64 + col]) + bias[col];
            mx = fmaxf(mx, vv[c]);
        } else {
            vv[c] = -INFINITY;
        }
    }
#pragma unroll
    for (int off = 1; off <= 8; off <<= 1)
        mx = fmaxf(mx, __shfl_xor(mx, off, 16));
    float sm = 0.f;
#pragma unroll
    for (int c = 0; c < 4; ++c)
        if (c0 + c < 47) sm += __expf(vv[c] - mx);
#pragma unroll
    for (int off = 1; off <= 8; off <<= 1)
        sm += __shfl_xor(sm, off, 16);
    float ls = __logf(sm);
    if (g == 0) {
#pragma unroll
        for (int c = 0; c < 4; ++c) {
            int col = c0 + c;
            if (col < 47) out[(size_t)n * 47 + col] = vv[c] - mx - ls;
        }
    }
}

// ---------------- launch ----------------

extern "C" void kernel_launch(void* const* d_in, const int* in_sizes, int n_in,
                              void* d_out, int out_size, void* d_ws, size_t ws_size,
                              hipStream_t stream) {
    const float* x   = (const float*)d_in[0];
    const int*   src = (const int*)d_in[1];
    const int*   dst = (const int*)d_in[2];
    const float* Wl0 = (const float*)d_in[3];
    const float* bl0 = (const float*)d_in[4];
    const float* Wr0 = (const float*)d_in[5];
    const float* Wl1 = (const float*)d_in[6];
    const float* bl1 = (const float*)d_in[7];
    const float* Wr1 = (const float*)d_in[8];
    const float* Wl2 = (const float*)d_in[9];
    const float* bl2 = (const float*)d_in[10];
    const float* Wr2 = (const float*)d_in[11];
    float* out = (float*)d_out;

    int N = in_sizes[0] / 128;
    int E = in_sizes[1];
    int nBuckets = (N + 255) >> BUCKET_SHIFT;

    char* ws = (char*)d_ws;
    size_t off = 0;
    auto alloc = [&](size_t bytes) -> char* {
        char* p = ws + off;
        off += (bytes + 255) & ~(size_t)255;
        return p;
    };
    int*   rowptr = (int*)alloc((size_t)(N + 1) * 4);
    float* invd   = (float*)alloc((size_t)N * 4);
    int*   ssrc   = (int*)alloc((size_t)E * 4);
    u16*   xb     = (u16*)alloc((size_t)N * 128 * 2);   // layer0 in, layer1 out, gemmG in
    u16*   h1     = (u16*)alloc((size_t)N * 128 * 2);   // layer0 out, layer1 in
    u16*   Gn     = (u16*)alloc((size_t)N * 64 * 2);    // neighbor projection (layer 2)
    u16*   Gs     = (u16*)alloc((size_t)N * 64 * 2);    // self projection (layer 2)
    int*   bucketCnt  = (int*)alloc(512 * 4);
    int*   bucketBase = (int*)alloc(520 * 4);
    int*   gcur   = (int*)alloc(512 * 4);
    u16*   wf0    = (u16*)alloc(32768 * 2);
    u16*   wf1    = (u16*)alloc(32768 * 2);
    u16*   wf2    = (u16*)alloc(16384 * 2);

    // interm (E uints = 6.4 MB) aliases Gn+Gs (25.6 MB): consumed by bucket_build
    // long before gemmG writes Gn/Gs.
    unsigned* interm = (unsigned*)Gn;

    int nChunks = (E + 16383) / 16384;

    hipMemsetAsync(bucketCnt, 0, 512 * 4, stream);
    bucket_count_kernel<<<nChunks, 256, 0, stream>>>(dst, bucketCnt, E, nBuckets);
    scan_buckets_kernel<<<1, 512, 0, stream>>>(bucketCnt, bucketBase, gcur, nBuckets);
    bucket_scatter_kernel<<<nChunks, 256, 0, stream>>>(src, dst, gcur, interm, E, nBuckets);
    bucket_build_kernel<<<nBuckets, 256, 0, stream>>>(interm, bucketBase, rowptr, invd,
                                                      ssrc, N);
    long total8 = (long)N * 16;  // N*128/8
    convert_kernel<<<(int)((total8 + 255) / 256), 256, 0, stream>>>(x, xb, total8);
    pack01_kernel<<<128, 256, 0, stream>>>(Wl0, Wr0, wf0);
    pack01_kernel<<<128, 256, 0, stream>>>(Wl1, Wr1, wf1);
    packl2_kernel<<<64, 256, 0, stream>>>(Wl2, Wr2, wf2);

    int gemmGrid = (N + 31) / 32;

    // layer 0: xb -> h1 (fused gather-agg + MFMA)
    sage_layer_mfma<<<gemmGrid, 256, 0, stream>>>((const uint4*)xb, rowptr, ssrc, invd,
                                                  wf0, bl0, h1, N);
    // layer 1: h1 -> xb (ping-pong)
    sage_layer_mfma<<<gemmGrid, 256, 0, stream>>>((const uint4*)h1, rowptr, ssrc, invd,
                                                  wf1, bl1, xb, N);
    // layer 2: [Gn|Gs] = xb @ Wp, then 128B-line gather + log_softmax
    gemmG_mfma<<<gemmGrid, 256, 0, stream>>>(xb, wf2, Gn, Gs, N);
    out_kernel<<<(N + 3) / 4, 256, 0, stream>>>((const uint2*)Gn, Gs, rowptr, ssrc, invd,
                                                bl2, out, N);
}

// Round 11
// 453.056 us; speedup vs baseline: 1.0156x; 1.0156x over previous
//
#include <hip/hip_runtime.h>
#include <math.h>

#define BUCKET_SHIFT 8  // 256 nodes per bucket

typedef short s8v __attribute__((ext_vector_type(8)));   // 8 bf16 (4 VGPRs)
typedef float f4v __attribute__((ext_vector_type(4)));   // 4 fp32 acc
typedef float f2v __attribute__((ext_vector_type(2)));
typedef unsigned short u16;

__device__ inline u16 f2bf(float f) {  // RNE fp32->bf16
    unsigned u = __float_as_uint(f);
    return (u16)((u + 0x7FFFu + ((u >> 16) & 1u)) >> 16);
}
__device__ inline float bf2f(u16 s) { return __uint_as_float(((unsigned)s) << 16); }
__device__ inline float blo(unsigned x) { return __uint_as_float(x << 16); }
__device__ inline float bhi(unsigned x) { return __uint_as_float(x & 0xffff0000u); }

// ---------------- CSR build (bucketed, no per-node global atomics) ----------------

__global__ __launch_bounds__(256) void bucket_count_kernel(const int* __restrict__ dst,
                                                           int* __restrict__ bucketCnt,
                                                           int n_edges, int nbuckets) {
    __shared__ int hist[512];
    int tid = threadIdx.x;
    for (int j = tid; j < nbuckets; j += 256) hist[j] = 0;
    __syncthreads();
    int e0 = blockIdx.x * 16384;
    int e1 = min(e0 + 16384, n_edges);
    for (int e = e0 + tid; e < e1; e += 256)
        atomicAdd(&hist[dst[e] >> BUCKET_SHIFT], 1);
    __syncthreads();
    for (int j = tid; j < nbuckets; j += 256) {
        int c = hist[j];
        if (c > 0) atomicAdd(&bucketCnt[j], c);
    }
}

__global__ __launch_bounds__(512) void scan_buckets_kernel(const int* __restrict__ bucketCnt,
                                                           int* __restrict__ bucketBase,
                                                           int* __restrict__ gcursor,
                                                           int nbuckets) {
    int tid = threadIdx.x;
    int c = (tid < nbuckets) ? bucketCnt[tid] : 0;
    int lane = tid & 63, wave = tid >> 6;
    int v = c;
#pragma unroll
    for (int off = 1; off < 64; off <<= 1) {
        int t = __shfl_up(v, off, 64);
        if (lane >= off) v += t;
    }
    __shared__ int wsum[8], woff[8];
    if (lane == 63) wsum[wave] = v;
    __syncthreads();
    if (tid == 0) {
        int run = 0;
#pragma unroll
        for (int w = 0; w < 8; ++w) { woff[w] = run; run += wsum[w]; }
    }
    __syncthreads();
    int excl = woff[wave] + (v - c);
    if (tid <= nbuckets) bucketBase[tid] = excl;
    if (tid < nbuckets) gcursor[tid] = excl;
}

__global__ __launch_bounds__(256) void bucket_scatter_kernel(const int* __restrict__ src,
                                                             const int* __restrict__ dst,
                                                             int* __restrict__ gcursor,
                                                             unsigned* __restrict__ interm,
                                                             int n_edges, int nbuckets) {
    __shared__ int hist[512];
    __shared__ int gbase[512];
    int tid = threadIdx.x;
    for (int j = tid; j < nbuckets; j += 256) hist[j] = 0;
    __syncthreads();
    int e0 = blockIdx.x * 16384;
    int e1 = min(e0 + 16384, n_edges);
    for (int e = e0 + tid; e < e1; e += 256)
        atomicAdd(&hist[dst[e] >> BUCKET_SHIFT], 1);
    __syncthreads();
    for (int j = tid; j < nbuckets; j += 256) {
        int c = hist[j];
        gbase[j] = c > 0 ? atomicAdd(&gcursor[j], c) : 0;
        hist[j] = 0;
    }
    __syncthreads();
    for (int e = e0 + tid; e < e1; e += 256) {
        int d = dst[e];
        int s = src[e];
        int j = d >> BUCKET_SHIFT;
        int p = atomicAdd(&hist[j], 1);
        interm[gbase[j] + p] = ((unsigned)s << 8) | (unsigned)(d & 255);
    }
}

__global__ __launch_bounds__(256) void bucket_build_kernel(const unsigned* __restrict__ interm,
                                                           const int* __restrict__ bucketBase,
                                                           int* __restrict__ rowptr,
                                                           float* __restrict__ invd,
                                                           int* __restrict__ ssrc, int n_nodes) {
    __shared__ int cnt[256];
    __shared__ int cur[256];
    __shared__ int wsum[4], woff[4];
    int tid = threadIdx.x;
    int nb0 = blockIdx.x << BUCKET_SHIFT;
    int base = bucketBase[blockIdx.x];
    int end = bucketBase[blockIdx.x + 1];
    cnt[tid] = 0;
    __syncthreads();
    for (int e = base + tid; e < end; e += 256)
        atomicAdd(&cnt[interm[e] & 255u], 1);
    __syncthreads();
    int c = cnt[tid];
    int lane = tid & 63, wave = tid >> 6;
    int v = c;
#pragma unroll
    for (int off = 1; off < 64; off <<= 1) {
        int t = __shfl_up(v, off, 64);
        if (lane >= off) v += t;
    }
    if (lane == 63) wsum[wave] = v;
    __syncthreads();
    if (tid == 0) {
        int run = 0;
#pragma unroll
        for (int w = 0; w < 4; ++w) { woff[w] = run; run += wsum[w]; }
    }
    __syncthreads();
    int excl = woff[wave] + (v - c);
    int node = nb0 + tid;
    if (node < n_nodes) {
        rowptr[node] = base + excl;
        invd[node] = c > 0 ? 1.0f / (float)c : 0.0f;
        if (node == n_nodes - 1) rowptr[n_nodes] = base + excl + c;
    }
    cur[tid] = base + excl;
    __syncthreads();
    for (int e = base + tid; e < end; e += 256) {
        unsigned p = interm[e];
        int pos = atomicAdd(&cur[p & 255u], 1);
        ssrc[pos] = (int)(p >> 8);
    }
}

// ---------------- x -> bf16 (xb) + fp8 (x8) ----------------
__global__ __launch_bounds__(256) void convert_kernel(const float* __restrict__ x,
                                                      u16* __restrict__ xb,
                                                      uint2* __restrict__ x8, long total8) {
    long i = (long)blockIdx.x * 256 + threadIdx.x;  // index of 8-elem chunk
    if (i >= total8) return;
    const float* p = &x[i * 8];
    float4 lo = *(const float4*)p;
    float4 hi = *(const float4*)(p + 4);
    union { u16 u[8]; s8v v; } t;
    t.u[0] = f2bf(lo.x); t.u[1] = f2bf(lo.y); t.u[2] = f2bf(lo.z); t.u[3] = f2bf(lo.w);
    t.u[4] = f2bf(hi.x); t.u[5] = f2bf(hi.y); t.u[6] = f2bf(hi.z); t.u[7] = f2bf(hi.w);
    *(s8v*)&xb[i * 8] = t.v;
    uint2 o;
    int r0 = __builtin_amdgcn_cvt_pk_fp8_f32(lo.x, lo.y, 0, false);
    r0 = __builtin_amdgcn_cvt_pk_fp8_f32(lo.z, lo.w, r0, true);
    int r1 = __builtin_amdgcn_cvt_pk_fp8_f32(hi.x, hi.y, 0, false);
    r1 = __builtin_amdgcn_cvt_pk_fp8_f32(hi.z, hi.w, r1, true);
    o.x = (unsigned)r0; o.y = (unsigned)r1;
    x8[i] = o;
}

// ---------------- bf16 features -> fp8 copy ----------------
__global__ __launch_bounds__(256) void tofp8_kernel(const u16* __restrict__ h,
                                                    uint2* __restrict__ h8, long total8) {
    long i = (long)blockIdx.x * 256 + threadIdx.x;
    if (i >= total8) return;
    s8v t = *(const s8v*)&h[i * 8];
    const u16* u = (const u16*)&t;
    int r0 = __builtin_amdgcn_cvt_pk_fp8_f32(bf2f(u[0]), bf2f(u[1]), 0, false);
    r0 = __builtin_amdgcn_cvt_pk_fp8_f32(bf2f(u[2]), bf2f(u[3]), r0, true);
    int r1 = __builtin_amdgcn_cvt_pk_fp8_f32(bf2f(u[4]), bf2f(u[5]), 0, false);
    r1 = __builtin_amdgcn_cvt_pk_fp8_f32(bf2f(u[6]), bf2f(u[7]), r1, true);
    uint2 o; o.x = (unsigned)r0; o.y = (unsigned)r1;
    h8[i] = o;
}

// ---------------- weight packing into MFMA fragment order ----------------
__global__ void pack01_kernel(const float* __restrict__ Wl, const float* __restrict__ Wr,
                              u16* __restrict__ out) {
    int idx = blockIdx.x * 256 + threadIdx.x;  // 256*128
    if (idx >= 32768) return;
    int k = idx >> 7, c = idx & 127;
    float v = (k < 128) ? Wl[k * 128 + c] : Wr[(k - 128) * 128 + c];
    int kt = k >> 5, q = (k >> 3) & 3, j = k & 7, ct = c >> 4, n = c & 15;
    out[(((kt * 8 + ct) * 64 + q * 16 + n) << 3) + j] = f2bf(v);
}

__global__ void packl2_kernel(const float* __restrict__ Wl, const float* __restrict__ Wr,
                              u16* __restrict__ out) {
    int idx = blockIdx.x * 256 + threadIdx.x;  // 128*128
    if (idx >= 16384) return;
    int k = idx >> 7, c = idx & 127;
    float v = 0.f;
    if (c < 47) v = Wl[k * 47 + c];
    else if (c >= 64 && c < 111) v = Wr[k * 47 + (c - 64)];
    int kt = k >> 5, q = (k >> 3) & 3, j = k & 7, ct = c >> 4, n = c & 15;
    out[(((kt * 8 + ct) * 64 + q * 16 + n) << 3) + j] = f2bf(v);
}

// ---------------- fused SAGE layer: fp8 gather-agg -> LDS A-tile -> MFMA ----------------
// hout = relu([mean_agg(hin) | hin] @ Wfrag + b).
// Gather path reads hin8 (fp8, 128 B/row); self path reads hin (bf16).
// Phase 1: 8 groups x 32 lanes; lane d covers 4 fp8 cols (one uint); x8 unrolled.
__global__ __launch_bounds__(256) void sage_layer_mfma(const unsigned* __restrict__ hin8,
                                                       const u16* __restrict__ hin,
                                                       const int* __restrict__ rowptr,
                                                       const int* __restrict__ ssrc,
                                                       const float* __restrict__ invd,
                                                       const u16* __restrict__ Wfrag,
                                                       const float* __restrict__ bias,
                                                       u16* __restrict__ hout, int n_nodes) {
    __shared__ u16 As[32][264];
    __shared__ int rp[33];
    int tid = threadIdx.x;
    int n0 = blockIdx.x * 32;
    if (tid < 33) rp[tid] = rowptr[min(n0 + tid, n_nodes)];
    __syncthreads();

    int d = tid & 31, grp = tid >> 5;  // 8 groups of 32 lanes

#pragma unroll
    for (int pass = 0; pass < 4; ++pass) {
        int row = pass * 8 + grp;
        int n = n0 + row;
        float a0 = 0.f, a1 = 0.f, a2 = 0.f, a3 = 0.f;
        int e = rp[row], e1 = rp[row + 1];
        for (; e + 7 < e1; e += 8) {
            int s[8];
#pragma unroll
            for (int j = 0; j < 8; ++j) s[j] = ssrc[e + j];
            unsigned w[8];
#pragma unroll
            for (int j = 0; j < 8; ++j) w[j] = hin8[(size_t)s[j] * 32 + d];
#pragma unroll
            for (int j = 0; j < 8; ++j) {
                f2v lo = __builtin_amdgcn_cvt_pk_f32_fp8(w[j], false);
                f2v hi = __builtin_amdgcn_cvt_pk_f32_fp8(w[j], true);
                a0 += lo.x; a1 += lo.y; a2 += hi.x; a3 += hi.y;
            }
        }
        for (; e < e1; ++e) {
            unsigned w0 = hin8[(size_t)ssrc[e] * 32 + d];
            f2v lo = __builtin_amdgcn_cvt_pk_f32_fp8(w0, false);
            f2v hi = __builtin_amdgcn_cvt_pk_f32_fp8(w0, true);
            a0 += lo.x; a1 += lo.y; a2 += hi.x; a3 += hi.y;
        }
        float wt = (n < n_nodes) ? invd[n] : 0.f;
        uint2 o;
        o.x = (unsigned)f2bf(a0 * wt) | ((unsigned)f2bf(a1 * wt) << 16);
        o.y = (unsigned)f2bf(a2 * wt) | ((unsigned)f2bf(a3 * wt) << 16);
        *(uint2*)&As[row][d * 4] = o;
    }

    // phase 2: stage self rows (bf16) into As cols 128..255
    for (int i = tid; i < 512; i += 256) {
        int row = i >> 4, c8 = i & 15;
        int n = n0 + row;
        s8v t = (s8v){0, 0, 0, 0, 0, 0, 0, 0};
        if (n < n_nodes) t = *(const s8v*)&hin[(size_t)n * 128 + c8 * 8];
        *(s8v*)&As[row][128 + c8 * 8] = t;
    }
    __syncthreads();

    // phase 3: MFMA, K=256
    int wave = tid >> 6, lane = tid & 63;
    int rt = wave & 1, ch = wave >> 1;
    int m = lane & 15, q = lane >> 4;

    f4v acc[4];
#pragma unroll
    for (int c = 0; c < 4; ++c) acc[c] = (f4v){0.f, 0.f, 0.f, 0.f};

#pragma unroll
    for (int kt = 0; kt < 8; ++kt) {
        s8v a = *(const s8v*)&As[rt * 16 + m][kt * 32 + q * 8];
#pragma unroll
        for (int c = 0; c < 4; ++c) {
            int ctg = ch * 4 + c;
            s8v b = *(const s8v*)&Wfrag[(((size_t)kt * 8 + ctg) * 64 + lane) * 8];
            acc[c] = __builtin_amdgcn_mfma_f32_16x16x32_bf16(a, b, acc[c], 0, 0, 0);
        }
    }

#pragma unroll
    for (int c = 0; c < 4; ++c) {
        int col = ch * 64 + c * 16 + m;
        float bc = bias[col];
#pragma unroll
        for (int r = 0; r < 4; ++r) {
            int n = n0 + rt * 16 + q * 4 + r;
            if (n < n_nodes)
                hout[(size_t)n * 128 + col] = f2bf(fmaxf(acc[c][r] + bc, 0.f));
        }
    }
}

// ---------------- MFMA GEMM: [Gn|Gs] = h @ Wfrag2 bf16, K=128 ----------------
__global__ __launch_bounds__(256) void gemmG_mfma(const u16* __restrict__ h,
                                                  const u16* __restrict__ Wfrag,
                                                  u16* __restrict__ Gn,
                                                  u16* __restrict__ Gs, int n_nodes) {
    __shared__ u16 As[32][136];
    int tid = threadIdx.x;
    int n0 = blockIdx.x * 32;
    for (int i = tid; i < 512; i += 256) {
        int row = i >> 4, c8 = i & 15;
        int n = n0 + row;
        s8v t = (s8v){0, 0, 0, 0, 0, 0, 0, 0};
        if (n < n_nodes) t = *(const s8v*)&h[(size_t)n * 128 + c8 * 8];
        *(s8v*)&As[row][c8 * 8] = t;
    }
    __syncthreads();

    int wave = tid >> 6, lane = tid & 63;
    int rt = wave & 1, ch = wave >> 1;
    int m = lane & 15, q = lane >> 4;

    f4v acc[4];
#pragma unroll
    for (int c = 0; c < 4; ++c) acc[c] = (f4v){0.f, 0.f, 0.f, 0.f};

#pragma unroll
    for (int kt = 0; kt < 4; ++kt) {
        s8v a = *(const s8v*)&As[rt * 16 + m][kt * 32 + q * 8];
#pragma unroll
        for (int c = 0; c < 4; ++c) {
            int ctg = ch * 4 + c;
            s8v b = *(const s8v*)&Wfrag[(((size_t)kt * 8 + ctg) * 64 + lane) * 8];
            acc[c] = __builtin_amdgcn_mfma_f32_16x16x32_bf16(a, b, acc[c], 0, 0, 0);
        }
    }

    u16* Gbase = (ch == 0) ? Gn : Gs;
#pragma unroll
    for (int c = 0; c < 4; ++c) {
        int col = c * 16 + m;
#pragma unroll
        for (int r = 0; r < 4; ++r) {
            int n = n0 + rt * 16 + q * 4 + r;
            if (n < n_nodes) Gbase[(size_t)n * 64 + col] = f2bf(acc[c][r]);
        }
    }
}

// ---------------- layer-2 epilogue: gather Gn (128B line/edge) + log_softmax ----------------
__global__ __launch_bounds__(256) void out_kernel(const u16* __restrict__ Gn,
                                                  const u16* __restrict__ Gs,
                                                  const int* __restrict__ rowptr,
                                                  const int* __restrict__ ssrc,
                                                  const float* __restrict__ inv_deg,
                                                  const float* __restrict__ bias,
                                                  float* __restrict__ out, int n_nodes) {
    int lane = threadIdx.x & 63;
    int n = blockIdx.x * 4 + (threadIdx.x >> 6);
    if (n >= n_nodes) return;
    bool ok = lane < 47;
    int e0 = rowptr[n], e1 = rowptr[n + 1];
    float acc = 0.f;
    int e = e0;
    for (; e + 7 < e1; e += 8) {
        int s[8];
#pragma unroll
        for (int j = 0; j < 8; ++j) s[j] = ssrc[e + j];
        float g[8];
#pragma unroll
        for (int j = 0; j < 8; ++j) g[j] = bf2f(Gn[(size_t)s[j] * 64 + lane]);
#pragma unroll
        for (int j = 0; j < 8; ++j) acc += g[j];
    }
    for (; e < e1; ++e) acc += bf2f(Gn[(size_t)ssrc[e] * 64 + lane]);

    float v = -INFINITY;
    if (ok) v = acc * inv_deg[n] + bf2f(Gs[(size_t)n * 64 + lane]) + bias[lane];

    float m = v;
#pragma unroll
    for (int off = 32; off >= 1; off >>= 1)
        m = fmaxf(m, __shfl_xor(m, off, 64));
    float s = ok ? __expf(v - m) : 0.f;
#pragma unroll
    for (int off = 32; off >= 1; off >>= 1)
        s += __shfl_xor(s, off, 64);
    float ls = __logf(s);
    if (ok) out[(size_t)n * 47 + lane] = v - m - ls;
}

// ---------------- launch ----------------

extern "C" void kernel_launch(void* const* d_in, const int* in_sizes, int n_in,
                              void* d_out, int out_size, void* d_ws, size_t ws_size,
                              hipStream_t stream) {
    const float* x   = (const float*)d_in[0];
    const int*   src = (const int*)d_in[1];
    const int*   dst = (const int*)d_in[2];
    const float* Wl0 = (const float*)d_in[3];
    const float* bl0 = (const float*)d_in[4];
    const float* Wr0 = (const float*)d_in[5];
    const float* Wl1 = (const float*)d_in[6];
    const float* bl1 = (const float*)d_in[7];
    const float* Wr1 = (const float*)d_in[8];
    const float* Wl2 = (const float*)d_in[9];
    const float* bl2 = (const float*)d_in[10];
    const float* Wr2 = (const float*)d_in[11];
    float* out = (float*)d_out;

    int N = in_sizes[0] / 128;
    int E = in_sizes[1];
    int nBuckets = (N + 255) >> BUCKET_SHIFT;

    char* ws = (char*)d_ws;
    size_t off = 0;
    auto alloc = [&](size_t bytes) -> char* {
        char* p = ws + off;
        off += (bytes + 255) & ~(size_t)255;
        return p;
    };
    int*   rowptr = (int*)alloc((size_t)(N + 1) * 4);
    float* invd   = (float*)alloc((size_t)N * 4);
    int*   ssrc   = (int*)alloc((size_t)E * 4);
    u16*   xb     = (u16*)alloc((size_t)N * 128 * 2);   // layer0 in (self), layer1 out, gemmG in
    u16*   h1     = (u16*)alloc((size_t)N * 128 * 2);   // layer0 out, layer1 in (self)
    u16*   Gn     = (u16*)alloc((size_t)N * 64 * 2);    // also: interm, then x8 (fp8 x)
    u16*   Gs     = (u16*)alloc((size_t)N * 64 * 2);    // also: h18 (fp8 h1)
    int*   bucketCnt  = (int*)alloc(512 * 4);
    int*   bucketBase = (int*)alloc(520 * 4);
    int*   gcur   = (int*)alloc(512 * 4);
    u16*   wf0    = (u16*)alloc(32768 * 2);
    u16*   wf1    = (u16*)alloc(32768 * 2);
    u16*   wf2    = (u16*)alloc(16384 * 2);

    // Aliasing timeline (all on one stream, so ordering is dispatch order):
    //   interm (6.4 MB, = Gn) : written by bucket_scatter, consumed by bucket_build.
    //   x8     (12.8 MB, = Gn): written by convert AFTER bucket_build, read by layer-0.
    //   h18    (12.8 MB, = Gs): written by tofp8 after layer-0, read by layer-1.
    //   Gn/Gs            : written by gemmG after layer-1 (x8/h18 then dead).
    unsigned* interm = (unsigned*)Gn;
    uint2*    x8     = (uint2*)Gn;
    uint2*    h18    = (uint2*)Gs;

    int nChunks = (E + 16383) / 16384;

    hipMemsetAsync(bucketCnt, 0, 512 * 4, stream);
    bucket_count_kernel<<<nChunks, 256, 0, stream>>>(dst, bucketCnt, E, nBuckets);
    scan_buckets_kernel<<<1, 512, 0, stream>>>(bucketCnt, bucketBase, gcur, nBuckets);
    bucket_scatter_kernel<<<nChunks, 256, 0, stream>>>(src, dst, gcur, interm, E, nBuckets);
    bucket_build_kernel<<<nBuckets, 256, 0, stream>>>(interm, bucketBase, rowptr, invd,
                                                      ssrc, N);
    long total8 = (long)N * 16;  // N*128/8
    convert_kernel<<<(int)((total8 + 255) / 256), 256, 0, stream>>>(x, xb, x8, total8);
    pack01_kernel<<<128, 256, 0, stream>>>(Wl0, Wr0, wf0);
    pack01_kernel<<<128, 256, 0, stream>>>(Wl1, Wr1, wf1);
    packl2_kernel<<<64, 256, 0, stream>>>(Wl2, Wr2, wf2);

    int gemmGrid = (N + 31) / 32;

    // layer 0: gather x8 (fp8) + self xb (bf16) -> h1
    sage_layer_mfma<<<gemmGrid, 256, 0, stream>>>((const unsigned*)x8, xb, rowptr, ssrc,
                                                  invd, wf0, bl0, h1, N);
    // h1 -> fp8 copy for layer-1 gather
    tofp8_kernel<<<(int)((total8 + 255) / 256), 256, 0, stream>>>(h1, h18, total8);
    // layer 1: gather h18 (fp8) + self h1 (bf16) -> xb (ping-pong)
    sage_layer_mfma<<<gemmGrid, 256, 0, stream>>>((const unsigned*)h18, h1, rowptr, ssrc,
                                                  invd, wf1, bl1, xb, N);
    // layer 2: [Gn|Gs] = xb @ Wp (clobbers x8/h18 — both dead), then gather + log_softmax
    gemmG_mfma<<<gemmGrid, 256, 0, stream>>>(xb, wf2, Gn, Gs, N);
    out_kernel<<<(N + 3) / 4, 256, 0, stream>>>(Gn, Gs, rowptr, ssrc, invd, bl2, out, N);
}